// Round 5
// baseline (1607.152 us; speedup 1.0000x reference)
//
#include <hip/hip_runtime.h>
#include <hip/hip_bf16.h>

#define N_NODES 100000
#define F_IN    256
#define H_DIM   128
#define C_CLS   16
#define NB_SCAN ((N_NODES + 255) / 256)   // 391

typedef __attribute__((ext_vector_type(8))) short  short8;
typedef __attribute__((ext_vector_type(8))) unsigned short ushort8;
typedef __attribute__((ext_vector_type(4))) float  float4v;
typedef __attribute__((ext_vector_type(4))) unsigned short ushort4v;

__device__ __forceinline__ float b2f(ushort u) {
    union { unsigned int i; float f; } v;
    v.i = ((unsigned int)u) << 16;
    return v.f;
}

__device__ __forceinline__ ushort f2b(float f) {
    unsigned int x = __float_as_uint(f);
    unsigned int r = (x + 0x7FFFu + ((x >> 16) & 1u)) >> 16;   // RNE
    return (ushort)r;
}

__device__ __forceinline__ float ldsel(const void* p, int i, int f32f) {
    return f32f ? ((const float*)p)[i] : b2f(((const ushort*)p)[i]);
}

// ------------------------------------------------------------------ sniff ---
__global__ __launch_bounds__(64) void sniff(const ushort* __restrict__ x,
                                            const int* __restrict__ ei,
                                            int* __restrict__ flags) {
    int lane = threadIdx.x;
    int cnt_bf = 0;
#pragma unroll
    for (int j = 0; j < 4; ++j) {
        ushort u = x[lane * 4 + j];
        int e = (u >> 7) & 0xFF;
        if ((e >= 100 && e <= 140) || (u & 0x7FFF) == 0) cnt_bf++;
    }
    int zodd = (ei[2 * lane + 1] == 0) ? 1 : 0;
#pragma unroll
    for (int off = 32; off >= 1; off >>= 1) {
        cnt_bf += __shfl_xor(cnt_bf, off, 64);
        zodd   += __shfl_xor(zodd,   off, 64);
    }
    if (lane == 0) {
        flags[0] = (cnt_bf < 230) ? 1 : 0;   // f32 inputs
        flags[1] = (zodd  >= 32) ? 1 : 0;    // int64 indices
    }
}

// -------------------------------------------------- f32 -> bf16 conversion --
__global__ __launch_bounds__(256) void convert_f32(const int* __restrict__ flags,
                                                   const float* __restrict__ xf,
                                                   const float* __restrict__ Wf,
                                                   ushort* __restrict__ xb,
                                                   ushort* __restrict__ wb) {
    if (flags[0] == 0) return;
    long i = ((long)blockIdx.x * 256 + threadIdx.x) * 4;
    const long NX = (long)N_NODES * F_IN;
    const long TOT = NX + (long)F_IN * H_DIM;
    if (i < NX) {
        float4 v = *(const float4*)(xf + i);
        ushort4v o;
        o[0] = f2b(v.x); o[1] = f2b(v.y); o[2] = f2b(v.z); o[3] = f2b(v.w);
        *(ushort4v*)(xb + i) = o;
    } else if (i < TOT) {
        long j = i - NX;
        float4 v = *(const float4*)(Wf + j);
        ushort4v o;
        o[0] = f2b(v.x); o[1] = f2b(v.y); o[2] = f2b(v.z); o[3] = f2b(v.w);
        *(ushort4v*)(wb + j) = o;
    }
}

// ---------------------- prep: ei -> int32 src/dst arrays + degree count -----
__global__ __launch_bounds__(256) void prep(const int* __restrict__ flags,
                                            const int* __restrict__ ei,
                                            int* __restrict__ src32,
                                            int* __restrict__ dst32,
                                            int* __restrict__ cnt, int E) {
    int e = blockIdx.x * 256 + threadIdx.x;
    if (e >= E) return;
    int i64 = flags[1];
    int s = i64 ? ei[2L * e]          : ei[e];
    int d = i64 ? ei[2L * E + 2L * e] : ei[(long)E + e];
    src32[e] = s;
    dst32[e] = d;
    atomicAdd(&cnt[d], 1);
}

// ------------------------------------------------------------ 3-step scan ---
__global__ __launch_bounds__(256) void scan1(const int* __restrict__ cnt,
                                             int* __restrict__ offs,
                                             int* __restrict__ bsum) {
    __shared__ int sd[256];
    int t = threadIdx.x;
    int i = blockIdx.x * 256 + t;
    int v = (i < N_NODES) ? cnt[i] : 0;
    sd[t] = v;
    __syncthreads();
#pragma unroll
    for (int d = 1; d < 256; d <<= 1) {
        int add = (t >= d) ? sd[t - d] : 0;
        __syncthreads();
        sd[t] += add;
        __syncthreads();
    }
    if (i < N_NODES) offs[i] = sd[t] - v;          // exclusive within block
    if (t == 255) bsum[blockIdx.x] = sd[255];
}

__global__ __launch_bounds__(512) void scan2(const int* __restrict__ bsum,
                                             int* __restrict__ boff) {
    __shared__ int sd[512];
    int t = threadIdx.x;
    int v = (t < NB_SCAN) ? bsum[t] : 0;
    sd[t] = v;
    __syncthreads();
#pragma unroll
    for (int d = 1; d < 512; d <<= 1) {
        int add = (t >= d) ? sd[t - d] : 0;
        __syncthreads();
        sd[t] += add;
        __syncthreads();
    }
    if (t < NB_SCAN) boff[t] = sd[t] - v;          // exclusive
}

// offs -> global offsets; also cursor copy and dis = rsqrt(deg) fused
__global__ __launch_bounds__(256) void scan3(int* __restrict__ offs,
                                             const int* __restrict__ boff,
                                             const int* __restrict__ cnt,
                                             int* __restrict__ cursor,
                                             float* __restrict__ dis, int E) {
    int i = blockIdx.x * 256 + threadIdx.x;
    if (i == 0) offs[N_NODES] = E;
    if (i >= N_NODES) return;
    int off = offs[i] + boff[i >> 8];
    offs[i] = off;
    cursor[i] = off;
    dis[i] = rsqrtf((float)(cnt[i] + 1));          // +1 self-loop
}

// ------------------------------------------------------ permutation build ---
__global__ __launch_bounds__(256) void build_perm(const int* __restrict__ src32,
                                                  const int* __restrict__ dst32,
                                                  int* __restrict__ cursor,
                                                  int* __restrict__ perm, int E) {
    int e = blockIdx.x * 256 + threadIdx.x;
    if (e >= E) return;
    int s = src32[e];
    int d = dst32[e];
    int slot = atomicAdd(&cursor[d], 1);
    perm[slot] = s;
}

// -------------------------------------------------------------- h = x @ W ---
__global__ __launch_bounds__(256) void gemm_xw(const int* __restrict__ flags,
                                               const ushort* __restrict__ x_raw,
                                               const ushort* __restrict__ xb,
                                               const ushort* __restrict__ W_raw,
                                               const ushort* __restrict__ wb,
                                               ushort* __restrict__ hout) {
    __shared__ __align__(16) ushort wt[128][128 + 8];   // 34816 B
    const int f32f = flags[0];
    const ushort* x = f32f ? xb : x_raw;
    const ushort* W = f32f ? wb : W_raw;

    const int tid  = threadIdx.x;
    const int lane = tid & 63;
    const int wave = tid >> 6;
    const int quad = lane >> 4;
    const int lm   = lane & 15;

    const int rbase = blockIdx.x * 64 + wave * 16;
    int arow = rbase + lm;
    if (arow >= N_NODES) arow = N_NODES - 1;      // clamp; store is guarded
    const ushort* xrow = x + (size_t)arow * F_IN;

    float4v acc[8];
#pragma unroll
    for (int c = 0; c < 8; ++c) acc[c] = (float4v){0.f, 0.f, 0.f, 0.f};

    for (int hh = 0; hh < 2; ++hh) {
        if (hh) __syncthreads();
#pragma unroll
        for (int it = 0; it < 8; ++it) {
            int flat = (it * 256 + tid) * 8;       // 0..16384
            int kl = flat >> 7;
            int c0 = flat & 127;
            short8 v = *(const short8*)(W + hh * 16384 + flat);
#pragma unroll
            for (int j = 0; j < 8; ++j) wt[c0 + j][kl] = (ushort)v[j];
        }
        __syncthreads();
#pragma unroll
        for (int s = 0; s < 4; ++s) {
            int klocal = s * 32 + quad * 8;
            short8 afrag = *(const short8*)(xrow + hh * 128 + klocal);
#pragma unroll
            for (int c = 0; c < 8; ++c) {
                short8 bfrag = *(const short8*)(&wt[c * 16 + lm][klocal]);
                acc[c] = __builtin_amdgcn_mfma_f32_16x16x32_bf16(afrag, bfrag, acc[c], 0, 0, 0);
            }
        }
    }
    // D[row=quad*4+r][col=lane&15]
#pragma unroll
    for (int c = 0; c < 8; ++c) {
        int col = c * 16 + lm;
#pragma unroll
        for (int r = 0; r < 4; ++r) {
            int node = rbase + quad * 4 + r;
            if (node < N_NODES) hout[(size_t)node * H_DIM + col] = f2b(acc[c][r]);
        }
    }
}

// ------------------- fused gather-reduce + bias/relu + bayes linear + lsm ---
// One wave per node; 16 lanes per edge-row (ushort8 = 16 B/lane), so one
// wave-load gathers 4 edge-rows and the 16-edge unrolled body keeps 4 loads
// (16 rows) in flight. (s,w) staged in wave-private LDS (no barriers),
// consumed via same-address ds_read_b64 broadcast within each quarter.
__global__ __launch_bounds__(256) void gather_final(const int* __restrict__ flags,
                                                    const int* __restrict__ offs,
                                                    const int* __restrict__ perm,
                                                    const float* __restrict__ dis,
                                                    const ushort* __restrict__ hb,
                                                    const void* __restrict__ gcn_b,
                                                    const void* __restrict__ w_mu,
                                                    const void* __restrict__ w_ls,
                                                    const void* __restrict__ b_mu,
                                                    const void* __restrict__ b_ls,
                                                    const void* __restrict__ eps_w,
                                                    const void* __restrict__ eps_b,
                                                    void* __restrict__ out) {
    __shared__ int2 sw[4][64];
    const int f32f = flags[0];
    const int lane = threadIdx.x & 63;
    const int wv   = threadIdx.x >> 6;
    const int q    = lane >> 4;        // quarter: which edge of a 4-group
    const int l4   = lane & 15;
    const int col8 = l4 * 8;           // this lane's 8 columns
    const int node = blockIdx.x * 4 + wv;   // N % 4 == 0 -> always valid

    const int off0 = offs[node];
    const int deg  = offs[node + 1] - off0;

    float ax[8];
#pragma unroll
    for (int k = 0; k < 8; ++k) ax[k] = 0.f;

    for (int base = 0; base < deg; base += 64) {
        int rem = deg - base;
        if (rem > 64) rem = 64;
        int sv = 0; float wl = 0.f;
        if (lane < rem) {
            sv = perm[off0 + base + lane];
            wl = dis[sv];
        }
        sw[wv][lane] = make_int2(sv, __float_as_int(wl));
        // wave-private LDS: in-order DS pipe, no barrier needed
        int jj = 0;
        for (; jj + 16 <= rem; jj += 16) {
            int2 p0 = sw[wv][jj + q];
            int2 p1 = sw[wv][jj + 4 + q];
            int2 p2 = sw[wv][jj + 8 + q];
            int2 p3 = sw[wv][jj + 12 + q];
            ushort8 u0 = *(const ushort8*)(hb + (size_t)p0.x * H_DIM + col8);
            ushort8 u1 = *(const ushort8*)(hb + (size_t)p1.x * H_DIM + col8);
            ushort8 u2 = *(const ushort8*)(hb + (size_t)p2.x * H_DIM + col8);
            ushort8 u3 = *(const ushort8*)(hb + (size_t)p3.x * H_DIM + col8);
            float w0 = __int_as_float(p0.y), w1 = __int_as_float(p1.y);
            float w2 = __int_as_float(p2.y), w3 = __int_as_float(p3.y);
#pragma unroll
            for (int k = 0; k < 8; ++k) {
                ax[k] = fmaf(w0, b2f(u0[k]), ax[k]);
                ax[k] = fmaf(w1, b2f(u1[k]), ax[k]);
                ax[k] = fmaf(w2, b2f(u2[k]), ax[k]);
                ax[k] = fmaf(w3, b2f(u3[k]), ax[k]);
            }
        }
        for (; jj + 4 <= rem; jj += 4) {
            int2 p0 = sw[wv][jj + q];
            ushort8 u0 = *(const ushort8*)(hb + (size_t)p0.x * H_DIM + col8);
            float w0 = __int_as_float(p0.y);
#pragma unroll
            for (int k = 0; k < 8; ++k) ax[k] = fmaf(w0, b2f(u0[k]), ax[k]);
        }
        if (jj < rem) {                       // tail: 1-3 edges of this chunk
            int e = jj + q;
            int2 p0 = (e < rem) ? sw[wv][e] : make_int2(0, 0);
            ushort8 u0 = *(const ushort8*)(hb + (size_t)p0.x * H_DIM + col8);
            float w0 = __int_as_float(p0.y);  // 0 for inactive quarters
#pragma unroll
            for (int k = 0; k < 8; ++k) ax[k] = fmaf(w0, b2f(u0[k]), ax[k]);
        }
    }

    // combine the 4 quarters (each accumulated a disjoint edge subset)
#pragma unroll
    for (int k = 0; k < 8; ++k) {
        ax[k] += __shfl_xor(ax[k], 32, 64);
        ax[k] += __shfl_xor(ax[k], 16, 64);
    }

    // self-loop + bias + relu (identical in all quarters)
    float dd = dis[node];
    float self = dd * dd;
    ushort8 us = *(const ushort8*)(hb + (size_t)node * H_DIM + col8);
    float a[8];
#pragma unroll
    for (int k = 0; k < 8; ++k) {
        float v = ax[k] * dd + b2f(us[k]) * self + ldsel(gcn_b, col8 + k, f32f);
        a[k] = fmaxf(v, 0.f);
    }

    // Bayes linear: quarter q handles classes 4q..4q+3
    float p[4];
#pragma unroll
    for (int cc = 0; cc < 4; ++cc) {
        int c = q * 4 + cc;
        float acc = 0.f;
#pragma unroll
        for (int k = 0; k < 8; ++k) {
            int i0 = c * H_DIM + col8 + k;
            float w = ldsel(w_mu, i0, f32f)
                    + __expf(ldsel(w_ls, i0, f32f)) * ldsel(eps_w, i0, f32f);
            acc = fmaf(a[k], w, acc);
        }
        p[cc] = acc;
    }
#pragma unroll
    for (int off = 8; off >= 1; off >>= 1) {
#pragma unroll
        for (int cc = 0; cc < 4; ++cc) p[cc] += __shfl_xor(p[cc], off, 64);
    }
#pragma unroll
    for (int cc = 0; cc < 4; ++cc) {
        int c = q * 4 + cc;
        p[cc] += ldsel(b_mu, c, f32f) + __expf(ldsel(b_ls, c, f32f)) * ldsel(eps_b, c, f32f);
    }

    // log-softmax across the 4 quarters
    float m = fmaxf(fmaxf(p[0], p[1]), fmaxf(p[2], p[3]));
    m = fmaxf(m, __shfl_xor(m, 16, 64));
    m = fmaxf(m, __shfl_xor(m, 32, 64));
    float s = __expf(p[0] - m) + __expf(p[1] - m) + __expf(p[2] - m) + __expf(p[3] - m);
    s += __shfl_xor(s, 16, 64);
    s += __shfl_xor(s, 32, 64);
    float lse = m + __logf(s);

    if (l4 == 0) {
        if (f32f) {
            float4 o;
            o.x = p[0] - lse; o.y = p[1] - lse; o.z = p[2] - lse; o.w = p[3] - lse;
            *(float4*)((float*)out + (size_t)node * C_CLS + q * 4) = o;
        } else {
            ushort4v o;
#pragma unroll
            for (int cc = 0; cc < 4; ++cc) o[cc] = f2b(p[cc] - lse);
            *(ushort4v*)((ushort*)out + (size_t)node * C_CLS + q * 4) = o;
        }
    }
}

// ---------------------------------------------------------------------------
extern "C" void kernel_launch(void* const* d_in, const int* in_sizes, int n_in,
                              void* d_out, int out_size, void* d_ws, size_t ws_size,
                              hipStream_t stream) {
    const int E = in_sizes[1] / 2;

    char* wp = (char*)d_ws;
    auto alloc = [&](size_t bytes) -> char* {
        char* p = wp; wp += (bytes + 511) & ~(size_t)511; return p;
    };
    int*    flags  = (int*)   alloc(64);
    ushort* hb     = (ushort*)alloc((size_t)N_NODES * H_DIM * 2);   // bf16 h
    int*    cnt    = (int*)   alloc((size_t)N_NODES * 4);
    int*    offs   = (int*)   alloc((size_t)(N_NODES + 1) * 4);
    int*    cursor = (int*)   alloc((size_t)N_NODES * 4);
    int*    bsum   = (int*)   alloc((size_t)NB_SCAN * 4);
    int*    boff   = (int*)   alloc((size_t)NB_SCAN * 4);
    float*  dis    = (float*) alloc((size_t)N_NODES * 4);
    int*    perm   = (int*)   alloc((size_t)E * 4);
    int*    src32  = (int*)   alloc((size_t)E * 4);
    int*    dst32  = (int*)   alloc((size_t)E * 4);
    ushort* xb     = (ushort*)alloc((size_t)N_NODES * F_IN * 2);
    ushort* wb     = (ushort*)alloc((size_t)F_IN * H_DIM * 2);

    sniff<<<1, 64, 0, stream>>>((const ushort*)d_in[0], (const int*)d_in[1], flags);
    {
        long tot = ((long)N_NODES * F_IN + (long)F_IN * H_DIM) / 4;
        convert_f32<<<(int)((tot + 255) / 256), 256, 0, stream>>>(
            flags, (const float*)d_in[0], (const float*)d_in[2], xb, wb);
    }
    (void)hipMemsetAsync(cnt, 0, (size_t)N_NODES * 4, stream);
    prep<<<(E + 255) / 256, 256, 0, stream>>>(flags, (const int*)d_in[1], src32, dst32, cnt, E);
    scan1<<<NB_SCAN, 256, 0, stream>>>(cnt, offs, bsum);
    scan2<<<1, 512, 0, stream>>>(bsum, boff);
    scan3<<<NB_SCAN, 256, 0, stream>>>(offs, boff, cnt, cursor, dis, E);
    build_perm<<<(E + 255) / 256, 256, 0, stream>>>(src32, dst32, cursor, perm, E);
    gemm_xw<<<(N_NODES + 63) / 64, 256, 0, stream>>>(flags,
                 (const ushort*)d_in[0], xb, (const ushort*)d_in[2], wb, hb);
    gather_final<<<(N_NODES + 3) / 4, 256, 0, stream>>>(flags, offs, perm, dis, hb,
                 d_in[3], d_in[4], d_in[5], d_in[6], d_in[7], d_in[8], d_in[9], (void*)d_out);
}

// Round 6
// 723.847 us; speedup vs baseline: 2.2203x; 2.2203x over previous
//
#include <hip/hip_runtime.h>
#include <hip/hip_bf16.h>

#define N_NODES 100000
#define F_IN    256
#define H_DIM   128
#define C_CLS   16
#define NB_SCAN ((N_NODES + 255) / 256)   // 391

typedef __attribute__((ext_vector_type(8))) short  short8;
typedef __attribute__((ext_vector_type(4))) float  float4v;
typedef __attribute__((ext_vector_type(4))) unsigned short ushort4v;

__device__ __forceinline__ float b2f(ushort u) {
    union { unsigned int i; float f; } v;
    v.i = ((unsigned int)u) << 16;
    return v.f;
}

__device__ __forceinline__ ushort f2b(float f) {
    unsigned int x = __float_as_uint(f);
    unsigned int r = (x + 0x7FFFu + ((x >> 16) & 1u)) >> 16;   // RNE
    return (ushort)r;
}

__device__ __forceinline__ float ldsel(const void* p, int i, int f32f) {
    return f32f ? ((const float*)p)[i] : b2f(((const ushort*)p)[i]);
}

// ------------------------------------------------------------------ sniff ---
__global__ __launch_bounds__(64) void sniff(const ushort* __restrict__ x,
                                            const int* __restrict__ ei,
                                            int* __restrict__ flags) {
    int lane = threadIdx.x;
    int cnt_bf = 0;
#pragma unroll
    for (int j = 0; j < 4; ++j) {
        ushort u = x[lane * 4 + j];
        int e = (u >> 7) & 0xFF;
        if ((e >= 100 && e <= 140) || (u & 0x7FFF) == 0) cnt_bf++;
    }
    int zodd = (ei[2 * lane + 1] == 0) ? 1 : 0;
#pragma unroll
    for (int off = 32; off >= 1; off >>= 1) {
        cnt_bf += __shfl_xor(cnt_bf, off, 64);
        zodd   += __shfl_xor(zodd,   off, 64);
    }
    if (lane == 0) {
        flags[0] = (cnt_bf < 230) ? 1 : 0;   // f32 inputs
        flags[1] = (zodd  >= 32) ? 1 : 0;    // int64 indices
    }
}

// -------------------------------------------------- f32 -> bf16 conversion --
__global__ __launch_bounds__(256) void convert_f32(const int* __restrict__ flags,
                                                   const float* __restrict__ xf,
                                                   const float* __restrict__ Wf,
                                                   ushort* __restrict__ xb,
                                                   ushort* __restrict__ wb) {
    if (flags[0] == 0) return;
    long i = ((long)blockIdx.x * 256 + threadIdx.x) * 4;
    const long NX = (long)N_NODES * F_IN;
    const long TOT = NX + (long)F_IN * H_DIM;
    if (i < NX) {
        float4 v = *(const float4*)(xf + i);
        ushort4v o;
        o[0] = f2b(v.x); o[1] = f2b(v.y); o[2] = f2b(v.z); o[3] = f2b(v.w);
        *(ushort4v*)(xb + i) = o;
    } else if (i < TOT) {
        long j = i - NX;
        float4 v = *(const float4*)(Wf + j);
        ushort4v o;
        o[0] = f2b(v.x); o[1] = f2b(v.y); o[2] = f2b(v.z); o[3] = f2b(v.w);
        *(ushort4v*)(wb + j) = o;
    }
}

// ---------------------- prep: ei -> int32 src/dst arrays + degree count -----
__global__ __launch_bounds__(256) void prep(const int* __restrict__ flags,
                                            const int* __restrict__ ei,
                                            int* __restrict__ src32,
                                            int* __restrict__ dst32,
                                            int* __restrict__ cnt, int E) {
    int e = blockIdx.x * 256 + threadIdx.x;
    if (e >= E) return;
    int i64 = flags[1];
    int s = i64 ? ei[2L * e]          : ei[e];
    int d = i64 ? ei[2L * E + 2L * e] : ei[(long)E + e];
    src32[e] = s;
    dst32[e] = d;
    atomicAdd(&cnt[d], 1);
}

// ------------------------------------------------------------ 3-step scan ---
__global__ __launch_bounds__(256) void scan1(const int* __restrict__ cnt,
                                             int* __restrict__ offs,
                                             int* __restrict__ bsum) {
    __shared__ int sd[256];
    int t = threadIdx.x;
    int i = blockIdx.x * 256 + t;
    int v = (i < N_NODES) ? cnt[i] : 0;
    sd[t] = v;
    __syncthreads();
#pragma unroll
    for (int d = 1; d < 256; d <<= 1) {
        int add = (t >= d) ? sd[t - d] : 0;
        __syncthreads();
        sd[t] += add;
        __syncthreads();
    }
    if (i < N_NODES) offs[i] = sd[t] - v;          // exclusive within block
    if (t == 255) bsum[blockIdx.x] = sd[255];
}

__global__ __launch_bounds__(512) void scan2(const int* __restrict__ bsum,
                                             int* __restrict__ boff) {
    __shared__ int sd[512];
    int t = threadIdx.x;
    int v = (t < NB_SCAN) ? bsum[t] : 0;
    sd[t] = v;
    __syncthreads();
#pragma unroll
    for (int d = 1; d < 512; d <<= 1) {
        int add = (t >= d) ? sd[t - d] : 0;
        __syncthreads();
        sd[t] += add;
        __syncthreads();
    }
    if (t < NB_SCAN) boff[t] = sd[t] - v;          // exclusive
}

// offs -> global offsets; also cursor copy and dis = rsqrt(deg) fused
__global__ __launch_bounds__(256) void scan3(int* __restrict__ offs,
                                             const int* __restrict__ boff,
                                             const int* __restrict__ cnt,
                                             int* __restrict__ cursor,
                                             float* __restrict__ dis, int E) {
    int i = blockIdx.x * 256 + threadIdx.x;
    if (i == 0) offs[N_NODES] = E;
    if (i >= N_NODES) return;
    int off = offs[i] + boff[i >> 8];
    offs[i] = off;
    cursor[i] = off;
    dis[i] = rsqrtf((float)(cnt[i] + 1));          // +1 self-loop
}

// ------------------------------------------------------ permutation build ---
// perm2[slot] = (src, dis[src]) so the gather loop has no dependent dis read
__global__ __launch_bounds__(256) void build_perm(const int* __restrict__ src32,
                                                  const int* __restrict__ dst32,
                                                  const float* __restrict__ dis,
                                                  int* __restrict__ cursor,
                                                  int2* __restrict__ perm2, int E) {
    int e = blockIdx.x * 256 + threadIdx.x;
    if (e >= E) return;
    int s = src32[e];
    int d = dst32[e];
    int slot = atomicAdd(&cursor[d], 1);
    perm2[slot] = make_int2(s, __float_as_int(dis[s]));
}

// -------------------------------------------------------------- h = x @ W ---
__global__ __launch_bounds__(256) void gemm_xw(const int* __restrict__ flags,
                                               const ushort* __restrict__ x_raw,
                                               const ushort* __restrict__ xb,
                                               const ushort* __restrict__ W_raw,
                                               const ushort* __restrict__ wb,
                                               ushort* __restrict__ hout) {
    __shared__ __align__(16) ushort wt[128][128 + 8];   // 34816 B
    const int f32f = flags[0];
    const ushort* x = f32f ? xb : x_raw;
    const ushort* W = f32f ? wb : W_raw;

    const int tid  = threadIdx.x;
    const int lane = tid & 63;
    const int wave = tid >> 6;
    const int quad = lane >> 4;
    const int lm   = lane & 15;

    const int rbase = blockIdx.x * 64 + wave * 16;
    int arow = rbase + lm;
    if (arow >= N_NODES) arow = N_NODES - 1;      // clamp; store is guarded
    const ushort* xrow = x + (size_t)arow * F_IN;

    float4v acc[8];
#pragma unroll
    for (int c = 0; c < 8; ++c) acc[c] = (float4v){0.f, 0.f, 0.f, 0.f};

    for (int hh = 0; hh < 2; ++hh) {
        if (hh) __syncthreads();
#pragma unroll
        for (int it = 0; it < 8; ++it) {
            int flat = (it * 256 + tid) * 8;       // 0..16384
            int kl = flat >> 7;
            int c0 = flat & 127;
            short8 v = *(const short8*)(W + hh * 16384 + flat);
#pragma unroll
            for (int j = 0; j < 8; ++j) wt[c0 + j][kl] = (ushort)v[j];
        }
        __syncthreads();
#pragma unroll
        for (int s = 0; s < 4; ++s) {
            int klocal = s * 32 + quad * 8;
            short8 afrag = *(const short8*)(xrow + hh * 128 + klocal);
#pragma unroll
            for (int c = 0; c < 8; ++c) {
                short8 bfrag = *(const short8*)(&wt[c * 16 + lm][klocal]);
                acc[c] = __builtin_amdgcn_mfma_f32_16x16x32_bf16(afrag, bfrag, acc[c], 0, 0, 0);
            }
        }
    }
    // D[row=quad*4+r][col=lane&15]
#pragma unroll
    for (int c = 0; c < 8; ++c) {
        int col = c * 16 + lm;
#pragma unroll
        for (int r = 0; r < 4; ++r) {
            int node = rbase + quad * 4 + r;
            if (node < N_NODES) hout[(size_t)node * H_DIM + col] = f2b(acc[c][r]);
        }
    }
}

// ------------------- fused gather-reduce + bias/relu + bayes linear + lsm ---
// One wave per node; lane owns cols {2l, 2l+1}. (s,w) pairs come packed from
// perm2 (one lane-parallel 8B load per 64 edges), broadcast via __shfl.
// Inner loop: uniform unroll-16 with zero-weight masking -> 16 independent
// 256B row-gathers in flight per batch, no tail branches (inactive slots
// gather row 0 with w=0).
__global__ __launch_bounds__(256) void gather_final(const int* __restrict__ flags,
                                                    const int* __restrict__ offs,
                                                    const int2* __restrict__ perm2,
                                                    const float* __restrict__ dis,
                                                    const ushort* __restrict__ hb,
                                                    const void* __restrict__ gcn_b,
                                                    const void* __restrict__ w_mu,
                                                    const void* __restrict__ w_ls,
                                                    const void* __restrict__ b_mu,
                                                    const void* __restrict__ b_ls,
                                                    const void* __restrict__ eps_w,
                                                    const void* __restrict__ eps_b,
                                                    void* __restrict__ out) {
    const int f32f = flags[0];
    const int lane = threadIdx.x & 63;
    const int node = blockIdx.x * 4 + (threadIdx.x >> 6);
    if (node >= N_NODES) return;

    const int off0 = offs[node];
    const int deg  = offs[node + 1] - off0;

    float ax = 0.f, ay = 0.f;
    for (int base = 0; base < deg; base += 64) {
        int rem = deg - base;
        if (rem > 64) rem = 64;
        int s_l = 0; float w_l = 0.f;
        if (lane < rem) {
            int2 pr = perm2[off0 + base + lane];
            s_l = pr.x;
            w_l = __int_as_float(pr.y);
        }
        // uniform batches of 16; slots >= rem have s=0,w=0 (harmless row-0 hit)
        for (int jj = 0; jj < rem; jj += 16) {
            int   sv[16];
            float wv[16];
#pragma unroll
            for (int k = 0; k < 16; ++k) {
                sv[k] = __shfl(s_l, jj + k, 64);
                wv[k] = __shfl(w_l, jj + k, 64);
            }
            uint u[16];
#pragma unroll
            for (int k = 0; k < 16; ++k)
                u[k] = *((const uint*)(hb + (size_t)sv[k] * H_DIM) + lane);
#pragma unroll
            for (int k = 0; k < 16; ++k) {
                float lo = __uint_as_float(u[k] << 16);
                float hi = __uint_as_float(u[k] & 0xFFFF0000u);
                ax = fmaf(wv[k], lo, ax);
                ay = fmaf(wv[k], hi, ay);
            }
        }
    }

    // self-loop + bias + relu (weights computed AFTER the loop: short live range)
    float dd = dis[node];
    uint us = *((const uint*)(hb + (size_t)node * H_DIM) + lane);
    float slo = __uint_as_float(us << 16);
    float shi = __uint_as_float(us & 0xFFFF0000u);
    ax = ax * dd + slo * dd * dd + ldsel(gcn_b, 2 * lane, f32f);
    ay = ay * dd + shi * dd * dd + ldsel(gcn_b, 2 * lane + 1, f32f);
    ax = fmaxf(ax, 0.f);
    ay = fmaxf(ay, 0.f);

    float p[C_CLS];
#pragma unroll
    for (int c = 0; c < C_CLS; ++c) {
        int i0 = c * H_DIM + 2 * lane;
        float wx = ldsel(w_mu, i0, f32f)     + __expf(ldsel(w_ls, i0, f32f))     * ldsel(eps_w, i0, f32f);
        float wy = ldsel(w_mu, i0 + 1, f32f) + __expf(ldsel(w_ls, i0 + 1, f32f)) * ldsel(eps_w, i0 + 1, f32f);
        p[c] = ax * wx + ay * wy;
    }
#pragma unroll
    for (int off = 32; off >= 1; off >>= 1) {
#pragma unroll
        for (int c = 0; c < C_CLS; ++c) p[c] += __shfl_xor(p[c], off, 64);
    }
#pragma unroll
    for (int c = 0; c < C_CLS; ++c)
        p[c] += ldsel(b_mu, c, f32f) + __expf(ldsel(b_ls, c, f32f)) * ldsel(eps_b, c, f32f);

    float m = p[0];
#pragma unroll
    for (int c = 1; c < C_CLS; ++c) m = fmaxf(m, p[c]);
    float ssum = 0.f;
#pragma unroll
    for (int c = 0; c < C_CLS; ++c) ssum += __expf(p[c] - m);
    float lse = m + __logf(ssum);

    if (lane == 0) {
        if (f32f) {
            float* op = (float*)out + (size_t)node * C_CLS;
            float4 o[4];
#pragma unroll
            for (int c = 0; c < C_CLS; ++c) ((float*)o)[c] = p[c] - lse;
#pragma unroll
            for (int q = 0; q < 4; ++q) ((float4*)op)[q] = o[q];
        } else {
            ushort* op = (ushort*)out + (size_t)node * C_CLS;
            ushort4v o[4];
#pragma unroll
            for (int c = 0; c < C_CLS; ++c) ((ushort*)o)[c] = f2b(p[c] - lse);
#pragma unroll
            for (int q = 0; q < 4; ++q) ((ushort4v*)op)[q] = o[q];
        }
    }
}

// ---------------------------------------------------------------------------
extern "C" void kernel_launch(void* const* d_in, const int* in_sizes, int n_in,
                              void* d_out, int out_size, void* d_ws, size_t ws_size,
                              hipStream_t stream) {
    const int E = in_sizes[1] / 2;

    char* wp = (char*)d_ws;
    auto alloc = [&](size_t bytes) -> char* {
        char* p = wp; wp += (bytes + 511) & ~(size_t)511; return p;
    };
    int*    flags  = (int*)   alloc(64);
    ushort* hb     = (ushort*)alloc((size_t)N_NODES * H_DIM * 2);   // bf16 h
    int*    cnt    = (int*)   alloc((size_t)N_NODES * 4);
    int*    offs   = (int*)   alloc((size_t)(N_NODES + 1) * 4);
    int*    cursor = (int*)   alloc((size_t)N_NODES * 4);
    int*    bsum   = (int*)   alloc((size_t)NB_SCAN * 4);
    int*    boff   = (int*)   alloc((size_t)NB_SCAN * 4);
    float*  dis    = (float*) alloc((size_t)N_NODES * 4);
    int2*   perm2  = (int2*)  alloc((size_t)E * 8);
    int*    src32  = (int*)   alloc((size_t)E * 4);
    int*    dst32  = (int*)   alloc((size_t)E * 4);
    ushort* xb     = (ushort*)alloc((size_t)N_NODES * F_IN * 2);
    ushort* wb     = (ushort*)alloc((size_t)F_IN * H_DIM * 2);

    sniff<<<1, 64, 0, stream>>>((const ushort*)d_in[0], (const int*)d_in[1], flags);
    {
        long tot = ((long)N_NODES * F_IN + (long)F_IN * H_DIM) / 4;
        convert_f32<<<(int)((tot + 255) / 256), 256, 0, stream>>>(
            flags, (const float*)d_in[0], (const float*)d_in[2], xb, wb);
    }
    (void)hipMemsetAsync(cnt, 0, (size_t)N_NODES * 4, stream);
    prep<<<(E + 255) / 256, 256, 0, stream>>>(flags, (const int*)d_in[1], src32, dst32, cnt, E);
    scan1<<<NB_SCAN, 256, 0, stream>>>(cnt, offs, bsum);
    scan2<<<1, 512, 0, stream>>>(bsum, boff);
    scan3<<<NB_SCAN, 256, 0, stream>>>(offs, boff, cnt, cursor, dis, E);
    build_perm<<<(E + 255) / 256, 256, 0, stream>>>(src32, dst32, dis, cursor, perm2, E);
    gemm_xw<<<(N_NODES + 63) / 64, 256, 0, stream>>>(flags,
                 (const ushort*)d_in[0], xb, (const ushort*)d_in[2], wb, hb);
    gather_final<<<(N_NODES + 3) / 4, 256, 0, stream>>>(flags, offs, perm2, dis, hb,
                 d_in[3], d_in[4], d_in[5], d_in[6], d_in[7], d_in[8], d_in[9], (void*)d_out);
}